// Round 7
// baseline (277.026 us; speedup 1.0000x reference)
//
#include <hip/hip_runtime.h>

#define N_ELEM 16777216
#define K 8                         // elements per thread-chunk
#define BLOCK 256
#define TILE (BLOCK * K)            // 2048 elements per block
#define NBLK (N_ELEM / TILE)        // 8192 blocks
#define INV_N (1.0 / (double)N_ELEM)

__global__ __launch_bounds__(BLOCK, 8) void k1_all(
        const float4* __restrict__ in4, const int4* __restrict__ lab4,
        const int* __restrict__ labs, float* __restrict__ out) {
    __shared__ unsigned metaS[BLOCK];   // h(6b) | firstLab<<6 | lastLab<<7
    __shared__ double wsum[BLOCK / 64];
    const int tid = threadIdx.x;
    const long long ch = (long long)blockIdx.x * BLOCK + tid;   // global chunk id

    // ---- phase A: 6 loads (4 float4 + 2 int4), all issued before any use ----
    float4 x[4];
    int4   lv[2];
    const float4* ip = in4 + ch * 4;    // 8 elems x 2 logits = 4 float4
    const int4*   lp = lab4 + ch * 2;   // 8 labels = 2 int4
    #pragma unroll
    for (int j = 0; j < 4; ++j) x[j] = ip[j];
    #pragma unroll
    for (int j = 0; j < 2; ++j) lv[j] = lp[j];

    // ---- phase B: backward run-scan over 8 elements, fully unrolled ----
    float acc = 0.f, tce = 0.f, cf = 0.f;
    int prevLab = 0, lastLab = 0, firstLab = 0;
    #pragma unroll
    for (int i = K - 1; i >= 0; --i) {
        float a = (i & 1) ? x[i >> 1].z : x[i >> 1].x;   // class-0 logit
        float b = (i & 1) ? x[i >> 1].w : x[i >> 1].y;   // class-1 logit
        int m = i & 3, l;
        { int4 q = lv[i >> 2];
          l = (m == 0) ? q.x : (m == 1) ? q.y : (m == 2) ? q.z : q.w; }
        float d = l ? (a - b) : (b - a);                 // x_other - x_label
        float ce = __logf(1.0f + __expf(d));             // CE = softplus(d)
        if (i == K - 1) { cf = 1.f; lastLab = l; }
        else            cf = (l == prevLab) ? cf + 1.f : 1.f;
        acc = fmaf(ce, cf, acc);                         // chunk-truncated weight
        if (cf == (float)(K - i)) tce += ce;             // element in trailing run
        prevLab = l;
        firstLab = l;
    }
    // after loop: cf = head run length h (<= 8, fits 6-bit field)
    metaS[tid] = (unsigned)cf | ((unsigned)firstLab << 6) | ((unsigned)lastLab << 7);
    __syncthreads();

    // ---- phase C: resolve trailing-run extension (expected ~1 step) ----
    long long ext = 0;
    {
        int prevLast = lastLab;
        int t = tid + 1;
        bool open = true;
        while (t < BLOCK) {
            unsigned mb = metaS[t];
            if ((int)((mb >> 6) & 1) != prevLast) { open = false; break; }
            int hb = (int)(mb & 63);
            ext += hb;
            if (hb < K) { open = false; break; }    // run ends inside chunk t
            prevLast = (int)((mb >> 7) & 1);
            ++t;
        }
        if (open) {                                 // run reaches tile end (rare)
            long long g = (long long)(blockIdx.x + 1) * TILE;
            while (g < N_ELEM && labs[g] == prevLast) { ++ext; ++g; }
        }
    }
    double accd = (double)acc + (double)tce * (double)ext;

    // ---- phase D: block reduce, one float atomic per block ----
    for (int o = 32; o; o >>= 1) accd += __shfl_down(accd, o);
    int wid = tid >> 6, lane = tid & 63;
    if (lane == 0) wsum[wid] = accd;
    __syncthreads();
    if (tid == 0) {
        double s = 0.0;
        for (int w = 0; w < BLOCK / 64; ++w) s += wsum[w];
        atomicAdd(out, (float)(s * INV_N));
    }
}

extern "C" void kernel_launch(void* const* d_in, const int* in_sizes, int n_in,
                              void* d_out, int out_size, void* d_ws, size_t ws_size,
                              hipStream_t stream) {
    const float* inputs = (const float*)d_in[0];
    const int* labels = (const int*)d_in[1];
    float* out = (float*)d_out;

    hipMemsetAsync(out, 0, sizeof(float), stream);   // 0x0 == 0.0f
    k1_all<<<NBLK, BLOCK, 0, stream>>>(
        (const float4*)inputs, (const int4*)labels, labels, out);
}

// Round 9
// 241.766 us; speedup vs baseline: 1.1458x; 1.1458x over previous
//
#include <hip/hip_runtime.h>

#define N_ELEM 16777216
#define K 16                        // elements per thread-chunk
#define BLOCK 256
#define TILE (BLOCK * K)            // 4096 elements per block
#define NBLK (N_ELEM / TILE)        // 4096 blocks
#define INV_N (1.0 / (double)N_ELEM)

__global__ __launch_bounds__(BLOCK, 4) void k1_all(
        const float4* __restrict__ in4, const int4* __restrict__ lab4,
        const int* __restrict__ labs, float* __restrict__ out) {
    __shared__ unsigned metaS[BLOCK];   // h(6b) | firstLab<<6 | lastLab<<7
    __shared__ double wsum[BLOCK / 64];
    const int tid = threadIdx.x;
    const long long ch = (long long)blockIdx.x * BLOCK + tid;   // global chunk id

    // ---- phase A: 12 loads (8 float4 + 4 int4), ALL issued before any use ----
    float4 x[8];                        // 16 elements x 2 logits
    int4   lv[4];                       // 16 labels
    const float4* ip = in4 + ch * 8;
    const int4*   lp = lab4 + ch * 4;
    #pragma unroll
    for (int j = 0; j < 8; ++j) x[j] = ip[j];
    #pragma unroll
    for (int j = 0; j < 4; ++j) lv[j] = lp[j];
    // Compiler fence: loads are memory ops and cannot sink below; all 12
    // destination registers are live here -> full-depth issue, max MLP.
    asm volatile("" ::: "memory");

    // ---- phase B: FORWARD run-scan (consume in load order) ----
    // Run [s,e]: sum ce_i*(e-i+1) = L*S0 - S1, L=run len, S1=sum ce*(i-s).
    float acc = 0.f, S0 = 0.f, S1 = 0.f, runStartF = 0.f;
    int prev = 0, firstLab = 0, h = K;
    #pragma unroll
    for (int i = 0; i < K; ++i) {
        float a = (i & 1) ? x[i >> 1].z : x[i >> 1].x;   // class-0 logit
        float b = (i & 1) ? x[i >> 1].w : x[i >> 1].y;   // class-1 logit
        int m = i & 3, l;
        { int4 q = lv[i >> 2];
          l = (m == 0) ? q.x : (m == 1) ? q.y : (m == 2) ? q.z : q.w; }
        float t = b - a;
        float d = l ? -t : t;                            // x_other - x_label
        float ce = __logf(1.0f + __expf(d));             // CE = softplus(d)
        if (i == 0) { firstLab = l; prev = l; }
        else if (l != prev) {                            // flush closed run
            float L = (float)i - runStartF;
            acc = fmaf(L, S0, acc) - S1;
            if (h == K) h = i;                           // first run length
            S0 = 0.f; S1 = 0.f; runStartF = (float)i;
            prev = l;
        }
        S0 += ce;
        S1 = fmaf(ce, (float)i - runStartF, S1);
    }
    const int lastLab = prev;
    const float tce = S0;                                // trailing-run CE sum
    acc = fmaf((float)K - runStartF, S0, acc) - S1;      // trailing run, local part

    metaS[tid] = (unsigned)h | ((unsigned)firstLab << 6) | ((unsigned)lastLab << 7);
    __syncthreads();

    // ---- phase C: resolve trailing-run extension (expected ~1 step) ----
    long long ext = 0;
    {
        int prevLast = lastLab;
        int t = tid + 1;
        bool open = true;
        while (t < BLOCK) {
            unsigned mb = metaS[t];
            if ((int)((mb >> 6) & 1) != prevLast) { open = false; break; }
            int hb = (int)(mb & 63);
            ext += hb;
            if (hb < K) { open = false; break; }    // run ends inside chunk t
            prevLast = (int)((mb >> 7) & 1);
            ++t;
        }
        if (open) {                                 // run reaches tile end (rare)
            long long g = (long long)(blockIdx.x + 1) * TILE;
            while (g < N_ELEM && labs[g] == prevLast) { ++ext; ++g; }
        }
    }
    double accd = (double)acc + (double)tce * (double)ext;

    // ---- phase D: block reduce, one float atomic per block ----
    for (int o = 32; o; o >>= 1) accd += __shfl_down(accd, o);
    int wid = tid >> 6, lane = tid & 63;
    if (lane == 0) wsum[wid] = accd;
    __syncthreads();
    if (tid == 0) {
        double s = 0.0;
        for (int w = 0; w < BLOCK / 64; ++w) s += wsum[w];
        atomicAdd(out, (float)(s * INV_N));
    }
}

extern "C" void kernel_launch(void* const* d_in, const int* in_sizes, int n_in,
                              void* d_out, int out_size, void* d_ws, size_t ws_size,
                              hipStream_t stream) {
    const float* inputs = (const float*)d_in[0];
    const int* labels = (const int*)d_in[1];
    float* out = (float*)d_out;

    hipMemsetAsync(out, 0, sizeof(float), stream);   // 0x0 == 0.0f
    k1_all<<<NBLK, BLOCK, 0, stream>>>(
        (const float4*)inputs, (const int4*)labels, labels, out);
}

// Round 10
// 233.423 us; speedup vs baseline: 1.1868x; 1.0357x over previous
//
#include <hip/hip_runtime.h>

#define N_ELEM 16777216
#define BLOCK 256
#define WPB 4                  // waves per block
#define SEGS 32                // 64-element segments per wave
#define SPAN (SEGS * 64)       // 2048 elements per wave
#define BSPAN (WPB * SPAN)     // 8192 elements per block
#define NBLK (N_ELEM / BSPAN)  // 2048 blocks = 8 per CU exactly
#define INV_N (1.0 / (double)N_ELEM)

__global__ __launch_bounds__(BLOCK) void k1_partial(
        const float2* __restrict__ in2, const int* __restrict__ labs,
        double* __restrict__ bsum) {
    __shared__ unsigned metaW[WPB];     // headLen(12b) | firstLab<<12 | lastLab<<13
    __shared__ double wtot[WPB];
    const int tid  = threadIdx.x;
    const int lane = tid & 63;
    const int w    = tid >> 6;
    const long long spanBase = (long long)blockIdx.x * BSPAN + (long long)w * SPAN;

    float acc = 0.f, pend = 0.f;
    unsigned headLen = SPAN;            // default: fully-uniform span
    int seen = 0;
    const float fopen = (float)(64 - lane);

    // ---- prefetch segment 0 (coalesced: 8B + 4B per lane) ----
    long long idx0 = spanBase + lane;
    float2 x  = in2[idx0];
    int   lab = labs[idx0];
    long long b0 = spanBase + 64;
    int  blab = labs[b0 < N_ELEM ? b0 : (N_ELEM - 1)];   // wave-uniform broadcast

    int firstLab = 0;

    #pragma unroll 1
    for (int s = 0; s < SEGS; ++s) {
        float2 xn; int labn = 0, blabn = 0;
        if (s + 1 < SEGS) {             // prefetch next segment (independent addrs)
            long long idn = spanBase + (long long)(s + 1) * 64 + lane;
            xn   = in2[idn];
            labn = labs[idn];
            long long bn = spanBase + (long long)(s + 2) * 64;
            blabn = labs[bn < N_ELEM ? bn : (N_ELEM - 1)];
        }
        if (s == 0) firstLab = __shfl(lab, 0);

        // CE = softplus(x_other - x_label)
        float t = x.y - x.x;
        float d = lab ? -t : t;
        float ce = __logf(1.0f + __expf(d));

        // per-lane next label: shfl for lanes 0..62, boundary broadcast for 63
        int nl = __shfl_down(lab, 1);
        long long bidx = spanBase + (long long)(s + 1) * 64;
        if (lane == 63) nl = (bidx < N_ELEM) ? blab : (lab ^ 1);

        unsigned long long Bm = __ballot(lab != nl);     // bit j: elem j ends a run
        unsigned long long sh = Bm >> lane;
        int   closed = (sh != 0ull);
        int   dist   = __ffsll(sh) - 1;                  // valid when closed
        float wloc   = closed ? (float)(dist + 1) : fopen;
        acc = fmaf(ce, wloc, acc);

        // close/extend pending runs from earlier segments (h is wave-uniform)
        int h = Bm ? __ffsll(Bm) : 64;
        acc  = fmaf(pend, (float)h, acc);
        pend = (Bm ? 0.f : pend) + (closed ? 0.f : ce);

        if (!seen && Bm) { headLen = (unsigned)(s * 64 + h); seen = 1; }

        if (s + 1 < SEGS) { x = xn; lab = labn; blab = blabn; }
    }
    const int lastLab = __shfl(lab, 63);

    // ---- wave reduce acc & pending-tail CE ----
    for (int o = 32; o; o >>= 1) {
        acc  += __shfl_down(acc,  o);
        pend += __shfl_down(pend, o);
    }
    if (lane == 0)
        metaW[w] = headLen | ((unsigned)firstLab << 12) | ((unsigned)lastLab << 13);
    __syncthreads();

    // ---- resolve trailing-run extension across waves (lane0 only) ----
    if (lane == 0) {
        long long ext = 0;
        if (pend != 0.f) {
            int prevLast = lastLab;
            int t2 = w + 1;
            bool open = true;
            while (t2 < WPB) {
                unsigned mb = metaW[t2];
                if ((int)((mb >> 12) & 1) != prevLast) { open = false; break; }
                unsigned hl = mb & 0xFFFu;
                ext += hl;
                if (hl < SPAN) { open = false; break; }
                prevLast = (int)((mb >> 13) & 1);
                ++t2;
            }
            if (open) {                 // run reaches block end (rare): global walk
                long long g = (long long)blockIdx.x * BSPAN + (long long)t2 * SPAN;
                while (g < N_ELEM && labs[g] == prevLast) { ++ext; ++g; }
            }
        }
        wtot[w] = (double)acc + (double)pend * (double)ext;
    }
    __syncthreads();
    if (tid == 0)
        bsum[blockIdx.x] = wtot[0] + wtot[1] + wtot[2] + wtot[3];
}

__global__ __launch_bounds__(BLOCK) void k2_final(
        const double* __restrict__ bsum, float* __restrict__ out) {
    double s = 0.0;
    for (int i = threadIdx.x; i < NBLK; i += BLOCK) s += bsum[i];
    for (int o = 32; o; o >>= 1) s += __shfl_down(s, o);
    __shared__ double wsum[BLOCK / 64];
    int wv = threadIdx.x >> 6, lane = threadIdx.x & 63;
    if (lane == 0) wsum[wv] = s;
    __syncthreads();
    if (threadIdx.x == 0)
        out[0] = (float)((wsum[0] + wsum[1] + wsum[2] + wsum[3]) * INV_N);
}

extern "C" void kernel_launch(void* const* d_in, const int* in_sizes, int n_in,
                              void* d_out, int out_size, void* d_ws, size_t ws_size,
                              hipStream_t stream) {
    const float* inputs = (const float*)d_in[0];
    const int* labels = (const int*)d_in[1];
    double* bsum = (double*)d_ws;       // 2048 * 8 B = 16 KB of workspace

    k1_partial<<<NBLK, BLOCK, 0, stream>>>(
        (const float2*)inputs, labels, bsum);
    k2_final<<<1, BLOCK, 0, stream>>>(bsum, (float*)d_out);
}